// Round 7
// baseline (300.389 us; speedup 1.0000x reference)
//
#include <hip/hip_runtime.h>
#include <cstdint>

#define NN 50000
#define NE 600000
#define NPAIRS 1563      // ceil(3125 tiles / 2): 32-row pairs
#define GSTRIDE 512      // persistent grid for k_gemm_f (2 blocks/CU, co-resident)

typedef unsigned short ushort_t;
typedef __bf16 bf16_t;
typedef __attribute__((ext_vector_type(8))) bf16_t bf16x8;
typedef __attribute__((ext_vector_type(8))) ushort_t ushort8;
typedef __attribute__((ext_vector_type(4))) float f32x4;
typedef __attribute__((ext_vector_type(2))) float f32x2;

// ---- ws layout (float offsets), extent ~16.15M fl = 64.6 MB ----
// WT   : [128 cols][640 k] bf16            @ 0           (40,960 fl)
// XG_G : [3126 tiles][64 g'][16 r][8] bf16 @ 40,960      (12,804,096 fl; G only)
// Xbf  : [NN][128] bf16 (node-major)       @ 12,845,056  (3,200,000 fl + pad)
// cnt  : [NN] i32                          @ 16,046,080
// curs : [NN] i32                          @ 16,096,080
// bsum/bscan : 128+128 i32                 @ 16,146,080 / 16,146,208
// colsum/colsq : 128+128 f32               @ 16,146,336 / 16,146,464
// done : 1 i32 (spin-barrier counter)      @ 16,146,592
#define WT_OFF   0ul
#define XGG_OFF  40960ul
#define XBF_OFF  12845056ul
#define CNT_OFF  16046080ul
#define CUR_OFF  16096080ul
#define BSUM_OFF 16146080ul
#define BSCN_OFF 16146208ul
#define CS_OFF   16146336ul
#define CSQ_OFF  16146464ul
#define DONE_OFF 16146592ul
// d_out transient: epack [NE] u32 @ 0 (dead before k_gemm_f writes out)

__device__ __forceinline__ float2 bf2_to_f2(uint32_t u) {
    float2 r;
    r.x = __uint_as_float(u << 16);
    r.y = __uint_as_float(u & 0xffff0000u);
    return r;
}

__device__ __forceinline__ ushort_t f2bf(float f) {
    uint32_t u = __float_as_uint(f);
    u = (u + 0x7fffu + ((u >> 16) & 1u)) >> 16;   // RNE
    return (ushort_t)u;
}

__device__ __forceinline__ uint32_t f2bf2(float x, float y) {
    return (uint32_t)f2bf(x) | ((uint32_t)f2bf(y) << 16);
}

__device__ __forceinline__ void async_copy16(const void* g, void* l) {
    __builtin_amdgcn_global_load_lds(
        (const __attribute__((address_space(1))) void*)g,
        (__attribute__((address_space(3))) void*)l, 16, 0, 0);
}

// ---------------------------------------------------------------------------
// K_pre: merged prep (blocks 0..319) + cast (320..3444) + hist (3445..5492).
// All three are mutually independent; merging saves 2 launch gaps.
//   prep: WT[n][kk] bf16; kk<128 -> Wl[kk][n]; kk>=128 -> bases
//   cast: X (f32) -> Xbf (bf16, node-major); no LDS transpose needed anymore
//   hist: atomicAdd dst histogram (2048 virtual blocks for latency depth)
// ---------------------------------------------------------------------------
__global__ __launch_bounds__(256) void k_pre(
    const float* __restrict__ X, const float* __restrict__ Wl,
    const float* __restrict__ bases, const int* __restrict__ eidx,
    ushort_t* __restrict__ WT, ushort_t* __restrict__ Xbf,
    int* __restrict__ cnt)
{
    const int b = blockIdx.x;
    const int tid = threadIdx.x;
    if (b < 320) {                         // ---- prep: 320*256 = 81920 ----
        const int i = b * 256 + tid;
        const int n = i / 640;
        const int kk = i - n * 640;
        float v;
        if (kk < 128) v = Wl[kk * 128 + n];
        else {
            const int j = kk - 128;
            v = bases[(size_t)(j >> 7) * 16384 + (j & 127) * 128 + n];
        }
        WT[i] = f2bf(v);
    } else if (b < 3445) {                 // ---- cast: 3125 tiles ----
        const int tile = b - 320;
        const int row = tid >> 4, gc = tid & 15;
        const int node = tile * 16 + row;                  // < NN
        const float4* p = (const float4*)(X + (size_t)node * 128 + gc * 8);
        const float4 a = p[0], c = p[1];
        ushort_t t8[8] = { f2bf(a.x), f2bf(a.y), f2bf(a.z), f2bf(a.w),
                           f2bf(c.x), f2bf(c.y), f2bf(c.z), f2bf(c.w) };
        *(uint4*)(Xbf + (size_t)node * 128 + gc * 8) = *(const uint4*)t8;
    } else {                               // ---- hist: 2048 blocks ----
        const int* __restrict__ dst = eidx + NE;
        for (int e = (b - 3445) * 256 + tid; e < NE; e += 2048 * 256)
            atomicAdd(cnt + dst[e], 1);
    }
}

// ---------------------------------------------------------------------------
// K3a/b/c: exclusive scan of cnt -> curs
// ---------------------------------------------------------------------------
__global__ __launch_bounds__(256) void k_scan1(
    const int* __restrict__ cnt, int* __restrict__ curs, int* __restrict__ bsum)
{
    __shared__ int sh[256];
    const int tid = threadIdx.x;
    const int i0 = blockIdx.x * 512 + tid * 2;
    const int v0 = (i0 < NN) ? cnt[i0] : 0;
    const int v1 = (i0 + 1 < NN) ? cnt[i0 + 1] : 0;
    int s = v0 + v1;
    sh[tid] = s;
    __syncthreads();
#pragma unroll
    for (int off = 1; off < 256; off <<= 1) {
        int t = (tid >= off) ? sh[tid - off] : 0;
        __syncthreads();
        sh[tid] += t;
        __syncthreads();
    }
    const int excl = sh[tid] - s;
    if (i0 < NN) curs[i0] = excl;
    if (i0 + 1 < NN) curs[i0 + 1] = excl + v0;
    if (tid == 255) bsum[blockIdx.x] = sh[255];
}

__global__ __launch_bounds__(128) void k_scan2(
    const int* __restrict__ bsum, int* __restrict__ bscan, int nblk)
{
    __shared__ int sh[128];
    const int tid = threadIdx.x;
    int v = (tid < nblk) ? bsum[tid] : 0;
    sh[tid] = v;
    __syncthreads();
#pragma unroll
    for (int off = 1; off < 128; off <<= 1) {
        int t = (tid >= off) ? sh[tid - off] : 0;
        __syncthreads();
        sh[tid] += t;
        __syncthreads();
    }
    if (tid < nblk) bscan[tid] = sh[tid] - v;
}

__global__ __launch_bounds__(256) void k_scan3(
    int* __restrict__ curs, const int* __restrict__ bscan)
{
    const int add = bscan[blockIdx.x];
    const int i0 = blockIdx.x * 512 + threadIdx.x * 2;
    if (i0 < NN) curs[i0] += add;
    if (i0 + 1 < NN) curs[i0 + 1] += add;
}

// ---------------------------------------------------------------------------
// K4: scatter edges into CSR slots. epack = src | (type<<16). grid 2048.
// ---------------------------------------------------------------------------
__global__ __launch_bounds__(256) void k_scatter(
    const int* __restrict__ eidx, const int* __restrict__ etype,
    int* __restrict__ curs, uint32_t* __restrict__ epack)
{
    const int* __restrict__ src = eidx;
    const int* __restrict__ dst = eidx + NE;
    for (int e = blockIdx.x * 256 + threadIdx.x; e < NE; e += gridDim.x * 256) {
        const int d = dst[e];
        const int pos = atomicAdd(curs + d, 1);
        epack[pos] = (uint32_t)src[e] | ((uint32_t)etype[e] << 16);
    }
}

// ---------------------------------------------------------------------------
// K5: gather (R15 structure): pk-fma accumulators + depth-8 load batching.
// Output layout updated: XG_G G-only, [tile][g'=b*16+k][row][8], stride
// 8192 ushorts (4096 u32) per tile.
// ---------------------------------------------------------------------------
__device__ __forceinline__ void accum_pk(
    const uint4 xv, const float4 cw, f32x2* m2)   // m2[16] = [b][c2]
{
    f32x2 x2[4];
    float2 p;
    p = bf2_to_f2(xv.x); x2[0] = f32x2{p.x, p.y};
    p = bf2_to_f2(xv.y); x2[1] = f32x2{p.x, p.y};
    p = bf2_to_f2(xv.z); x2[2] = f32x2{p.x, p.y};
    p = bf2_to_f2(xv.w); x2[3] = f32x2{p.x, p.y};
#pragma unroll
    for (int c2 = 0; c2 < 4; ++c2) {
        m2[0 * 4 + c2] += cw.x * x2[c2];
        m2[1 * 4 + c2] += cw.y * x2[c2];
        m2[2 * 4 + c2] += cw.z * x2[c2];
        m2[3 * 4 + c2] += cw.w * x2[c2];
    }
}

__global__ __launch_bounds__(256, 4) void k_gather(
    const ushort_t* __restrict__ Xbf, const uint32_t* __restrict__ epack,
    const int* __restrict__ cnt, const int* __restrict__ curs,
    const float* __restrict__ coeff, ushort_t* __restrict__ XG_G)
{
    const int lane = threadIdx.x & 63;
    const int w = threadIdx.x >> 6;
    const int sub = lane >> 4;     // node within wave's 4
    const int k = lane & 15;       // col block (8 cols)
    const int tile = blockIdx.x;
    const int d = tile * 16 + w * 4 + sub;   // grid=3125 -> d<NN

    const int n = cnt[d];
    const int end = curs[d];       // post-scatter: end offset
    int j = end - n;

    f32x2 m2[16];
#pragma unroll
    for (int i = 0; i < 16; ++i) m2[i] = f32x2{0.f, 0.f};

    for (; j + 7 < end; j += 8) {
        uint32_t ep[8];
#pragma unroll
        for (int i = 0; i < 8; ++i) ep[i] = epack[j + i];
        uint4 xv[8];
        float4 cw[8];
#pragma unroll
        for (int i = 0; i < 8; ++i) {
            const int s = ep[i] & 0xffff;
            const int t = ep[i] >> 16;
            xv[i] = *(const uint4*)(Xbf + (size_t)s * 128 + k * 8);
            cw[i] = *(const float4*)(coeff + t * 4);
        }
#pragma unroll
        for (int i = 0; i < 8; ++i) accum_pk(xv[i], cw[i], m2);
    }
    if (j + 3 < end) {
        uint32_t ep[4];
#pragma unroll
        for (int i = 0; i < 4; ++i) ep[i] = epack[j + i];
        uint4 xv[4];
        float4 cw[4];
#pragma unroll
        for (int i = 0; i < 4; ++i) {
            const int s = ep[i] & 0xffff;
            const int t = ep[i] >> 16;
            xv[i] = *(const uint4*)(Xbf + (size_t)s * 128 + k * 8);
            cw[i] = *(const float4*)(coeff + t * 4);
        }
#pragma unroll
        for (int i = 0; i < 4; ++i) accum_pk(xv[i], cw[i], m2);
        j += 4;
    }
    for (; j < end; ++j) {
        const uint32_t ep = epack[j];
        const int s = ep & 0xffff;
        const int t = ep >> 16;
        const uint4 xv = *(const uint4*)(Xbf + (size_t)s * 128 + k * 8);
        const float4 cw = *(const float4*)(coeff + t * 4);
        accum_pk(xv, cw, m2);
    }

    uint32_t* gb = (uint32_t*)(XG_G + (size_t)tile * 8192);
#pragma unroll
    for (int b = 0; b < 4; ++b) {
        uint4 v;
        v.x = f2bf2(m2[b * 4 + 0][0], m2[b * 4 + 0][1]);
        v.y = f2bf2(m2[b * 4 + 1][0], m2[b * 4 + 1][1]);
        v.z = f2bf2(m2[b * 4 + 2][0], m2[b * 4 + 2][1]);
        v.w = f2bf2(m2[b * 4 + 3][0], m2[b * 4 + 3][1]);
        *(uint4*)(gb + (b * 16 + k) * 64 + (w * 4 + sub) * 4) = v;
    }
}

// ---------------------------------------------------------------------------
// K6: FUSED projection + BatchNorm + ReLU (R17).
//  * persistent grid=512; __launch_bounds__(256,2) HARD-CAPS VGPR at 256 so
//    2 blocks/CU (80KB LDS) is guaranteed -> all 512 blocks co-resident ->
//    device-scope spin barrier is deadlock-free by construction.
//  * X fragments staged directly from node-major Xbf (per-lane global addr,
//    linear LDS dest); G fragments from XG_G. k_cast's transpose removed.
//  * after pair loop: stats atomics -> release done++ -> acquire spin to 512
//    -> re-read OWN rows (own-XCD L2) -> BN+ReLU -> final store.
//    Kills k_bn_relu's 51 MB HBM round-trip.
// ---------------------------------------------------------------------------
__global__ __launch_bounds__(256, 2) void k_gemm_f(
    const ushort_t* __restrict__ XG_G, const ushort_t* __restrict__ WT,
    const ushort_t* __restrict__ Xbf, const float* __restrict__ bl,
    const int* __restrict__ cnt, const float* __restrict__ gamma,
    const float* __restrict__ beta, float* __restrict__ out,
    float* __restrict__ colsum, float* __restrict__ colsq,
    int* __restrict__ done)
{
    __shared__ ushort_t As[2][2][10240];   // [buf][tile-of-pair][80g x 16r x 8]
    const int tid = threadIdx.x;
    const int lane = tid & 63;
    const int w = tid >> 6;
    const int m = lane & 15;
    const int quad = lane >> 4;

    // waves 0,1 -> tile0 halves; waves 2,3 -> tile1 (wave-uniform LDS dest)
    auto stage = [&](ushort_t* __restrict__ d0, ushort_t* __restrict__ d1,
                     int pr) {
        const int tl = w >> 1;
        const int tile = pr * 2 + tl;
        ushort_t* d = tl ? d1 : d0;
        const int off0 = (w & 1) * 10;
#pragma unroll
        for (int j = 0; j < 10; ++j) {
            const int off = off0 + j;
            const ushort_t* src;
            if (off < 4) {     // X chunk: per-lane source from Xbf
                const int node = tile * 16 + (lane & 15);
                const int g = off * 4 + (lane >> 4);
                src = Xbf + (size_t)node * 128 + g * 8;
            } else {           // G chunk: linear from XG_G
                src = XG_G + (size_t)tile * 8192 + (off - 4) * 512 + lane * 8;
            }
            async_copy16(src, d + off * 512);
        }
    };

    const ushort_t* bp0 = WT + (size_t)(w * 32 + m) * 640 + quad * 8;
    const ushort_t* bp1 = bp0 + 16 * 640;
    ushort8 B0[20], B1[20];
    const float blv0 = bl[w * 32 + m];
    const float blv1 = bl[w * 32 + 16 + m];
    float s0 = 0.f, q0 = 0.f, s1 = 0.f, q1 = 0.f;

    auto compute = [&](const ushort_t* __restrict__ A0,
                       const ushort_t* __restrict__ A1, int pr) {
        f32x4 cc[2][2];
#pragma unroll
        for (int rt = 0; rt < 2; ++rt)
#pragma unroll
            for (int ct = 0; ct < 2; ++ct)
#pragma unroll
                for (int i = 0; i < 4; ++i) cc[rt][ct][i] = 0.f;

#pragma unroll
        for (int c = 0; c < 20; ++c) {
            const int aoff = (c * 4 + quad) * 128 + m * 8;
            const bf16x8 a0 = __builtin_bit_cast(bf16x8, *(const ushort8*)&A0[aoff]);
            const bf16x8 a1 = __builtin_bit_cast(bf16x8, *(const ushort8*)&A1[aoff]);
            const bf16x8 b0 = __builtin_bit_cast(bf16x8, B0[c]);
            const bf16x8 b1 = __builtin_bit_cast(bf16x8, B1[c]);
            cc[0][0] = __builtin_amdgcn_mfma_f32_16x16x32_bf16(a0, b0, cc[0][0], 0, 0, 0);
            cc[0][1] = __builtin_amdgcn_mfma_f32_16x16x32_bf16(a0, b1, cc[0][1], 0, 0, 0);
            cc[1][0] = __builtin_amdgcn_mfma_f32_16x16x32_bf16(a1, b0, cc[1][0], 0, 0, 0);
            cc[1][1] = __builtin_amdgcn_mfma_f32_16x16x32_bf16(a1, b1, cc[1][1], 0, 0, 0);
        }

        const int row0 = pr * 32;
#pragma unroll
        for (int rt = 0; rt < 2; ++rt) {
            const int rowb = row0 + rt * 16 + quad * 4;
#pragma unroll
            for (int r = 0; r < 4; ++r) {
                const int row = rowb + r;
                if (row < NN) {
                    const int dg = cnt[row];
                    const float inv = 1.0f / (float)((dg > 0) ? dg : 1);
                    float* po = out + (size_t)row * 128 + w * 32 + m;
                    const float v0 = (cc[rt][0][r] + blv0) * inv;
                    const float v1 = (cc[rt][1][r] + blv1) * inv;
                    po[0]  = v0;           // raw; rewritten post-barrier
                    po[16] = v1;
                    s0 += v0; q0 += v0 * v0;
                    s1 += v1; q1 += v1 * v1;
                }
            }
        }
    };

    // ---- prologue ----
    int p = blockIdx.x;
    stage(As[0][0], As[0][1], p);
#pragma unroll
    for (int c = 0; c < 20; ++c) {
        B0[c] = *(const ushort8*)(bp0 + c * 32);
        B1[c] = *(const ushort8*)(bp1 + c * 32);
    }
    __syncthreads();

    while (true) {
        int pn = p + GSTRIDE;
        if (pn < NPAIRS) stage(As[1][0], As[1][1], pn);
        compute(As[0][0], As[0][1], p);
        if (pn >= NPAIRS) break;
        __syncthreads();
        p = pn;

        pn = p + GSTRIDE;
        if (pn < NPAIRS) stage(As[0][0], As[0][1], pn);
        compute(As[1][0], As[1][1], p);
        if (pn >= NPAIRS) break;
        __syncthreads();
        p = pn;
    }

    // ---- stats to global ----
    s0 += __shfl_down(s0, 32); q0 += __shfl_down(q0, 32);
    s0 += __shfl_down(s0, 16); q0 += __shfl_down(q0, 16);
    s1 += __shfl_down(s1, 32); q1 += __shfl_down(q1, 32);
    s1 += __shfl_down(s1, 16); q1 += __shfl_down(q1, 16);
    if (lane < 16) {
        atomicAdd(colsum + w * 32 + lane, s0);
        atomicAdd(colsq  + w * 32 + lane, q0);
        atomicAdd(colsum + w * 32 + 16 + lane, s1);
        atomicAdd(colsq  + w * 32 + 16 + lane, q1);
    }

    // ---- grid spin barrier (512 co-resident blocks, guaranteed) ----
    __syncthreads();                  // all waves' atomics issued & drained
    if (tid == 0) {
        __threadfence();
        atomicAdd(done, 1);
        while (__hip_atomic_load(done, __ATOMIC_ACQUIRE,
                                 __HIP_MEMORY_SCOPE_AGENT) < GSTRIDE)
            __builtin_amdgcn_s_sleep(4);
    }
    __syncthreads();

    // ---- BN params for this thread's two columns ----
    const int c0 = w * 32 + m, c1 = c0 + 16;
    const float cs0 = __hip_atomic_load(colsum + c0, __ATOMIC_RELAXED,
                                        __HIP_MEMORY_SCOPE_AGENT);
    const float cq0 = __hip_atomic_load(colsq + c0, __ATOMIC_RELAXED,
                                        __HIP_MEMORY_SCOPE_AGENT);
    const float cs1 = __hip_atomic_load(colsum + c1, __ATOMIC_RELAXED,
                                        __HIP_MEMORY_SCOPE_AGENT);
    const float cq1 = __hip_atomic_load(colsq + c1, __ATOMIC_RELAXED,
                                        __HIP_MEMORY_SCOPE_AGENT);
    const float mean0 = cs0 * (1.0f / NN);
    const float var0  = cq0 * (1.0f / NN) - mean0 * mean0;
    const float g0 = gamma[c0] * rsqrtf(var0 + 1e-5f);
    const float h0 = beta[c0] - mean0 * g0;
    const float mean1 = cs1 * (1.0f / NN);
    const float var1  = cq1 * (1.0f / NN) - mean1 * mean1;
    const float g1 = gamma[c1] * rsqrtf(var1 + 1e-5f);
    const float h1 = beta[c1] - mean1 * g1;

    // ---- normalize own rows (own-XCD L2-resident) ----
    for (int pp = blockIdx.x; pp < NPAIRS; pp += GSTRIDE) {
        const int row0 = pp * 32;
#pragma unroll
        for (int rt = 0; rt < 2; ++rt) {
            const int rowb = row0 + rt * 16 + quad * 4;
#pragma unroll
            for (int r = 0; r < 4; ++r) {
                const int row = rowb + r;
                if (row < NN) {
                    float* po = out + (size_t)row * 128 + w * 32 + m;
                    po[0]  = fmaxf(fmaf(po[0],  g0, h0), 0.f);
                    po[16] = fmaxf(fmaf(po[16], g1, h1), 0.f);
                }
            }
        }
    }
}

extern "C" void kernel_launch(void* const* d_in, const int* in_sizes, int n_in,
                              void* d_out, int out_size, void* d_ws, size_t ws_size,
                              hipStream_t stream)
{
    const float* X      = (const float*)d_in[0];
    const float* bases  = (const float*)d_in[1];
    const float* coeff  = (const float*)d_in[2];
    const float* Wl     = (const float*)d_in[3];
    const float* bl     = (const float*)d_in[4];
    const float* gamma  = (const float*)d_in[5];
    const float* beta   = (const float*)d_in[6];
    const int*   eidx   = (const int*)d_in[7];
    const int*   etype  = (const int*)d_in[8];
    float* out = (float*)d_out;

    float* ws = (float*)d_ws;
    ushort_t* WT     = (ushort_t*)(ws + WT_OFF);
    ushort_t* XG_G   = (ushort_t*)(ws + XGG_OFF);
    ushort_t* Xbf    = (ushort_t*)(ws + XBF_OFF);
    int*      cnt    = (int*)(ws + CNT_OFF);
    int*      curs   = (int*)(ws + CUR_OFF);
    int*      bsum   = (int*)(ws + BSUM_OFF);
    int*      bscan  = (int*)(ws + BSCN_OFF);
    float*    colsum = ws + CS_OFF;
    float*    colsq  = ws + CSQ_OFF;
    int*      done   = (int*)(ws + DONE_OFF);
    uint32_t* epack  = (uint32_t*)d_out;   // dead before k_gemm_f writes out

    // zero cnt..done (includes colsum/colsq and the barrier counter)
    hipMemsetAsync(cnt, 0, (DONE_OFF + 1 - CNT_OFF) * sizeof(float), stream);

    const int nblk_scan = (NN + 511) / 512;   // 98

    k_pre<<<5493, 256, 0, stream>>>(X, Wl, bases, eidx, WT, Xbf, cnt);
    k_scan1<<<nblk_scan, 256, 0, stream>>>(cnt, curs, bsum);
    k_scan2<<<1, 128, 0, stream>>>(bsum, bscan, nblk_scan);
    k_scan3<<<nblk_scan, 256, 0, stream>>>(curs, bscan);
    k_scatter<<<2048, 256, 0, stream>>>(eidx, etype, curs, epack);
    k_gather<<<3125, 256, 0, stream>>>(Xbf, epack, cnt, curs, coeff, XG_G);
    k_gemm_f<<<GSTRIDE, 256, 0, stream>>>(XG_G, WT, Xbf, bl, cnt,
                                          gamma, beta, out, colsum, colsq, done);
}

// Round 8
// 243.865 us; speedup vs baseline: 1.2318x; 1.2318x over previous
//
#include <hip/hip_runtime.h>
#include <cstdint>

#define NN 50000
#define NE 600000
#define NPAIRS 1563      // ceil(3125 tiles / 2): 32-row pairs
#define GSTRIDE 512      // persistent grid for k_gemm_f (2 blocks/CU)

typedef unsigned short ushort_t;
typedef __bf16 bf16_t;
typedef __attribute__((ext_vector_type(8))) bf16_t bf16x8;
typedef __attribute__((ext_vector_type(8))) ushort_t ushort8;
typedef __attribute__((ext_vector_type(4))) float f32x4;
typedef __attribute__((ext_vector_type(2))) float f32x2;

// ---- ws layout (float offsets), extent ~16.15M fl = 64.6 MB ----
// WT   : [128 cols][640 k] bf16            @ 0           (40,960 fl)
// XG_G : [3126 tiles][64 g'][16 r][8] bf16 @ 40,960      (12,804,096 fl; G only)
// Xbf  : [NN][128] bf16 (node-major)       @ 12,845,056  (3,200,000 fl + pad)
// cnt  : [NN] i32                          @ 16,046,080
// curs : [NN] i32                          @ 16,096,080
// bsum/bscan : 128+128 i32                 @ 16,146,080 / 16,146,208
// colsum/colsq : 128+128 f32               @ 16,146,336 / 16,146,464
#define WT_OFF   0ul
#define XGG_OFF  40960ul
#define XBF_OFF  12845056ul
#define CNT_OFF  16046080ul
#define CUR_OFF  16096080ul
#define BSUM_OFF 16146080ul
#define BSCN_OFF 16146208ul
#define CS_OFF   16146336ul
#define CSQ_OFF  16146464ul
// d_out transient: epack [NE] u32 @ 0 (scatter -> gather; dead before k_gemm_f)

__device__ __forceinline__ float2 bf2_to_f2(uint32_t u) {
    float2 r;
    r.x = __uint_as_float(u << 16);
    r.y = __uint_as_float(u & 0xffff0000u);
    return r;
}

__device__ __forceinline__ ushort_t f2bf(float f) {
    uint32_t u = __float_as_uint(f);
    u = (u + 0x7fffu + ((u >> 16) & 1u)) >> 16;   // RNE
    return (ushort_t)u;
}

__device__ __forceinline__ uint32_t f2bf2(float x, float y) {
    return (uint32_t)f2bf(x) | ((uint32_t)f2bf(y) << 16);
}

__device__ __forceinline__ void async_copy16(const void* g, void* l) {
    __builtin_amdgcn_global_load_lds(
        (const __attribute__((address_space(1))) void*)g,
        (__attribute__((address_space(3))) void*)l, 16, 0, 0);
}

// ---------------------------------------------------------------------------
// K_pre: merged prep (blocks 0..319) + cast (320..3444) + hist (3445..5492).
// (verified correct in R7; keeps the 2-launch saving and drops k_cast's
// LDS transpose + 12.8 MB XG X-region write)
// ---------------------------------------------------------------------------
__global__ __launch_bounds__(256) void k_pre(
    const float* __restrict__ X, const float* __restrict__ Wl,
    const float* __restrict__ bases, const int* __restrict__ eidx,
    ushort_t* __restrict__ WT, ushort_t* __restrict__ Xbf,
    int* __restrict__ cnt)
{
    const int b = blockIdx.x;
    const int tid = threadIdx.x;
    if (b < 320) {                         // ---- prep: 320*256 = 81920 ----
        const int i = b * 256 + tid;
        const int n = i / 640;
        const int kk = i - n * 640;
        float v;
        if (kk < 128) v = Wl[kk * 128 + n];
        else {
            const int j = kk - 128;
            v = bases[(size_t)(j >> 7) * 16384 + (j & 127) * 128 + n];
        }
        WT[i] = f2bf(v);
    } else if (b < 3445) {                 // ---- cast: 3125 tiles ----
        const int tile = b - 320;
        const int row = tid >> 4, gc = tid & 15;
        const int node = tile * 16 + row;                  // < NN
        const float4* p = (const float4*)(X + (size_t)node * 128 + gc * 8);
        const float4 a = p[0], c = p[1];
        ushort_t t8[8] = { f2bf(a.x), f2bf(a.y), f2bf(a.z), f2bf(a.w),
                           f2bf(c.x), f2bf(c.y), f2bf(c.z), f2bf(c.w) };
        *(uint4*)(Xbf + (size_t)node * 128 + gc * 8) = *(const uint4*)t8;
    } else {                               // ---- hist: 2048 blocks ----
        const int* __restrict__ dst = eidx + NE;
        for (int e = (b - 3445) * 256 + tid; e < NE; e += 2048 * 256)
            atomicAdd(cnt + dst[e], 1);
    }
}

// ---------------------------------------------------------------------------
// K3a/b/c: exclusive scan of cnt -> curs
// ---------------------------------------------------------------------------
__global__ __launch_bounds__(256) void k_scan1(
    const int* __restrict__ cnt, int* __restrict__ curs, int* __restrict__ bsum)
{
    __shared__ int sh[256];
    const int tid = threadIdx.x;
    const int i0 = blockIdx.x * 512 + tid * 2;
    const int v0 = (i0 < NN) ? cnt[i0] : 0;
    const int v1 = (i0 + 1 < NN) ? cnt[i0 + 1] : 0;
    int s = v0 + v1;
    sh[tid] = s;
    __syncthreads();
#pragma unroll
    for (int off = 1; off < 256; off <<= 1) {
        int t = (tid >= off) ? sh[tid - off] : 0;
        __syncthreads();
        sh[tid] += t;
        __syncthreads();
    }
    const int excl = sh[tid] - s;
    if (i0 < NN) curs[i0] = excl;
    if (i0 + 1 < NN) curs[i0 + 1] = excl + v0;
    if (tid == 255) bsum[blockIdx.x] = sh[255];
}

__global__ __launch_bounds__(128) void k_scan2(
    const int* __restrict__ bsum, int* __restrict__ bscan, int nblk)
{
    __shared__ int sh[128];
    const int tid = threadIdx.x;
    int v = (tid < nblk) ? bsum[tid] : 0;
    sh[tid] = v;
    __syncthreads();
#pragma unroll
    for (int off = 1; off < 128; off <<= 1) {
        int t = (tid >= off) ? sh[tid - off] : 0;
        __syncthreads();
        sh[tid] += t;
        __syncthreads();
    }
    if (tid < nblk) bscan[tid] = sh[tid] - v;
}

__global__ __launch_bounds__(256) void k_scan3(
    int* __restrict__ curs, const int* __restrict__ bscan)
{
    const int add = bscan[blockIdx.x];
    const int i0 = blockIdx.x * 512 + threadIdx.x * 2;
    if (i0 < NN) curs[i0] += add;
    if (i0 + 1 < NN) curs[i0 + 1] += add;
}

// ---------------------------------------------------------------------------
// K4: scatter edges into CSR slots. epack = src | (type<<16). grid 2048.
// ---------------------------------------------------------------------------
__global__ __launch_bounds__(256) void k_scatter(
    const int* __restrict__ eidx, const int* __restrict__ etype,
    int* __restrict__ curs, uint32_t* __restrict__ epack)
{
    const int* __restrict__ src = eidx;
    const int* __restrict__ dst = eidx + NE;
    for (int e = blockIdx.x * 256 + threadIdx.x; e < NE; e += gridDim.x * 256) {
        const int d = dst[e];
        const int pos = atomicAdd(curs + d, 1);
        epack[pos] = (uint32_t)src[e] | ((uint32_t)etype[e] << 16);
    }
}

// ---------------------------------------------------------------------------
// K5: gather (R15, kept): pk-fma accumulators + depth-8 load batching.
// Writes G-only layout XG_G: [tile][g'=b*16+k][row][8], 8192 ushorts/tile.
// ---------------------------------------------------------------------------
__device__ __forceinline__ void accum_pk(
    const uint4 xv, const float4 cw, f32x2* m2)   // m2[16] = [b][c2]
{
    f32x2 x2[4];
    float2 p;
    p = bf2_to_f2(xv.x); x2[0] = f32x2{p.x, p.y};
    p = bf2_to_f2(xv.y); x2[1] = f32x2{p.x, p.y};
    p = bf2_to_f2(xv.z); x2[2] = f32x2{p.x, p.y};
    p = bf2_to_f2(xv.w); x2[3] = f32x2{p.x, p.y};
#pragma unroll
    for (int c2 = 0; c2 < 4; ++c2) {
        m2[0 * 4 + c2] += cw.x * x2[c2];
        m2[1 * 4 + c2] += cw.y * x2[c2];
        m2[2 * 4 + c2] += cw.z * x2[c2];
        m2[3 * 4 + c2] += cw.w * x2[c2];
    }
}

__global__ __launch_bounds__(256, 4) void k_gather(
    const ushort_t* __restrict__ Xbf, const uint32_t* __restrict__ epack,
    const int* __restrict__ cnt, const int* __restrict__ curs,
    const float* __restrict__ coeff, ushort_t* __restrict__ XG_G)
{
    const int lane = threadIdx.x & 63;
    const int w = threadIdx.x >> 6;
    const int sub = lane >> 4;     // node within wave's 4
    const int k = lane & 15;       // col block (8 cols)
    const int tile = blockIdx.x;
    const int d = tile * 16 + w * 4 + sub;   // grid=3125 -> d<NN

    const int n = cnt[d];
    const int end = curs[d];       // post-scatter: end offset
    int j = end - n;

    f32x2 m2[16];
#pragma unroll
    for (int i = 0; i < 16; ++i) m2[i] = f32x2{0.f, 0.f};

    for (; j + 7 < end; j += 8) {
        uint32_t ep[8];
#pragma unroll
        for (int i = 0; i < 8; ++i) ep[i] = epack[j + i];
        uint4 xv[8];
        float4 cw[8];
#pragma unroll
        for (int i = 0; i < 8; ++i) {
            const int s = ep[i] & 0xffff;
            const int t = ep[i] >> 16;
            xv[i] = *(const uint4*)(Xbf + (size_t)s * 128 + k * 8);
            cw[i] = *(const float4*)(coeff + t * 4);
        }
#pragma unroll
        for (int i = 0; i < 8; ++i) accum_pk(xv[i], cw[i], m2);
    }
    if (j + 3 < end) {
        uint32_t ep[4];
#pragma unroll
        for (int i = 0; i < 4; ++i) ep[i] = epack[j + i];
        uint4 xv[4];
        float4 cw[4];
#pragma unroll
        for (int i = 0; i < 4; ++i) {
            const int s = ep[i] & 0xffff;
            const int t = ep[i] >> 16;
            xv[i] = *(const uint4*)(Xbf + (size_t)s * 128 + k * 8);
            cw[i] = *(const float4*)(coeff + t * 4);
        }
#pragma unroll
        for (int i = 0; i < 4; ++i) accum_pk(xv[i], cw[i], m2);
        j += 4;
    }
    for (; j < end; ++j) {
        const uint32_t ep = epack[j];
        const int s = ep & 0xffff;
        const int t = ep >> 16;
        const uint4 xv = *(const uint4*)(Xbf + (size_t)s * 128 + k * 8);
        const float4 cw = *(const float4*)(coeff + t * 4);
        accum_pk(xv, cw, m2);
    }

    uint32_t* gb = (uint32_t*)(XG_G + (size_t)tile * 8192);
#pragma unroll
    for (int b = 0; b < 4; ++b) {
        uint4 v;
        v.x = f2bf2(m2[b * 4 + 0][0], m2[b * 4 + 0][1]);
        v.y = f2bf2(m2[b * 4 + 1][0], m2[b * 4 + 1][1]);
        v.z = f2bf2(m2[b * 4 + 2][0], m2[b * 4 + 2][1]);
        v.w = f2bf2(m2[b * 4 + 3][0], m2[b * 4 + 3][1]);
        *(uint4*)(gb + (b * 16 + k) * 64 + (w * 4 + sub) * 4) = v;
    }
}

// ---------------------------------------------------------------------------
// K6: projection — EXACT R5 structure (best measured: 41 µs, total 249.9),
// except the stage() now sources X chunks straight from node-major Xbf
// (per-lane global addr, linear LDS dest — verified in R7) and G chunks
// from the compact XG_G. No BN fusion, no spin barrier (R7 post-mortem:
// +68 µs). B-residency abandoned: compiler pins VGPR=128 regardless of
// launch bounds (R6/R7 evidence) — B reloads per pair are L2-hits.
// ---------------------------------------------------------------------------
__global__ __launch_bounds__(256, 2) void k_gemm_f(
    const ushort_t* __restrict__ XG_G, const ushort_t* __restrict__ WT,
    const ushort_t* __restrict__ Xbf, const float* __restrict__ bl,
    const int* __restrict__ cnt, float* __restrict__ out,
    float* __restrict__ colsum, float* __restrict__ colsq)
{
    __shared__ ushort_t As[2][2][10240];   // [buf][tile-of-pair][80g x 16r x 8]
    const int tid = threadIdx.x;
    const int lane = tid & 63;
    const int w = tid >> 6;
    const int m = lane & 15;
    const int quad = lane >> 4;

    // per-pair stage: 40 chunks x 1KB, 10 per wave.
    // chunk off<4: X from Xbf (per-lane src); off>=4: G from XG_G (linear)
    auto stage = [&](int buf, int pr) {
#pragma unroll
        for (int j = 0; j < 10; ++j) {
            const int idx = w * 10 + j;        // 0..39
            const int tl = idx / 20;
            const int off = idx - tl * 20;     // 0..19
            const int tile = pr * 2 + tl;
            const ushort_t* src;
            if (off < 4) {
                const int node = tile * 16 + (lane & 15);
                const int g = off * 4 + (lane >> 4);
                src = Xbf + (size_t)node * 128 + g * 8;
            } else {
                src = XG_G + (size_t)tile * 8192 + (off - 4) * 512 + lane * 8;
            }
            async_copy16(src, &As[buf][tl][off * 512]);
        }
    };

    // prologue: stage first pair, then load B while it flies
    int p = blockIdx.x;
    stage(0, p);

    const ushort_t* bp0 = WT + (size_t)(w * 32 + m) * 640 + quad * 8;
    const ushort_t* bp1 = bp0 + 16 * 640;
    ushort8 B0[20], B1[20];
#pragma unroll
    for (int c = 0; c < 20; ++c) {
        B0[c] = *(const ushort8*)(bp0 + c * 32);
        B1[c] = *(const ushort8*)(bp1 + c * 32);
    }
    const float blv0 = bl[w * 32 + m];
    const float blv1 = bl[w * 32 + 16 + m];
    float s0 = 0.f, q0 = 0.f, s1 = 0.f, q1 = 0.f;

    __syncthreads();   // drains prologue stage

    int buf = 0;
    while (p < NPAIRS) {
        const int pn = p + GSTRIDE;
        if (pn < NPAIRS) stage(buf ^ 1, pn);   // flies under compute below

        f32x4 cc[2][2];
#pragma unroll
        for (int rt = 0; rt < 2; ++rt)
#pragma unroll
            for (int ct = 0; ct < 2; ++ct)
#pragma unroll
                for (int i = 0; i < 4; ++i) cc[rt][ct][i] = 0.f;

#pragma unroll
        for (int c = 0; c < 20; ++c) {
            const int aoff = (c * 4 + quad) * 128 + m * 8;  // c*1KB + lane*16B
            const bf16x8 a0 = __builtin_bit_cast(bf16x8, *(const ushort8*)&As[buf][0][aoff]);
            const bf16x8 a1 = __builtin_bit_cast(bf16x8, *(const ushort8*)&As[buf][1][aoff]);
            const bf16x8 b0 = __builtin_bit_cast(bf16x8, B0[c]);
            const bf16x8 b1 = __builtin_bit_cast(bf16x8, B1[c]);
            cc[0][0] = __builtin_amdgcn_mfma_f32_16x16x32_bf16(a0, b0, cc[0][0], 0, 0, 0);
            cc[0][1] = __builtin_amdgcn_mfma_f32_16x16x32_bf16(a0, b1, cc[0][1], 0, 0, 0);
            cc[1][0] = __builtin_amdgcn_mfma_f32_16x16x32_bf16(a1, b0, cc[1][0], 0, 0, 0);
            cc[1][1] = __builtin_amdgcn_mfma_f32_16x16x32_bf16(a1, b1, cc[1][1], 0, 0, 0);
        }

        // epilogue: degree-norm, store, stats accumulate (regs)
        const int row0 = p * 32;
#pragma unroll
        for (int rt = 0; rt < 2; ++rt) {
            const int rowb = row0 + rt * 16 + quad * 4;
#pragma unroll
            for (int r = 0; r < 4; ++r) {
                const int row = rowb + r;
                if (row < NN) {
                    const int dg = cnt[row];
                    const float inv = 1.0f / (float)((dg > 0) ? dg : 1);
                    float* po = out + (size_t)row * 128 + w * 32 + m;
                    const float v0 = (cc[rt][0][r] + blv0) * inv;
                    const float v1 = (cc[rt][1][r] + blv1) * inv;
                    po[0]  = v0;
                    po[16] = v1;
                    s0 += v0; q0 += v0 * v0;
                    s1 += v1; q1 += v1 * v1;
                }
            }
        }

        if (pn < NPAIRS) __syncthreads();  // drain stage(buf^1) + release buf
        buf ^= 1;
        p = pn;
    }

    s0 += __shfl_down(s0, 32); q0 += __shfl_down(q0, 32);
    s0 += __shfl_down(s0, 16); q0 += __shfl_down(q0, 16);
    s1 += __shfl_down(s1, 32); q1 += __shfl_down(q1, 32);
    s1 += __shfl_down(s1, 16); q1 += __shfl_down(q1, 16);
    if (lane < 16) {
        atomicAdd(colsum + w * 32 + lane, s0);
        atomicAdd(colsq  + w * 32 + lane, q0);
        atomicAdd(colsum + w * 32 + 16 + lane, s1);
        atomicAdd(colsq  + w * 32 + 16 + lane, q1);
    }
}

// ---------------------------------------------------------------------------
// K7: BatchNorm (batch stats) + ReLU, in place on d_out.
// ---------------------------------------------------------------------------
__global__ __launch_bounds__(256) void k_bn_relu(
    float* __restrict__ out, const float* __restrict__ colsum,
    const float* __restrict__ colsq, const float* __restrict__ gamma,
    const float* __restrict__ beta)
{
    __shared__ float sc[128], sh[128];
    const int tid = threadIdx.x;
    if (tid < 128) {
        const float mean = colsum[tid] * (1.0f / NN);
        const float var = colsq[tid] * (1.0f / NN) - mean * mean;
        const float g = gamma[tid] * rsqrtf(var + 1e-5f);
        sc[tid] = g;
        sh[tid] = beta[tid] - mean * g;
    }
    __syncthreads();
    const int total = NN * 32;
    for (int i = blockIdx.x * 256 + tid; i < total; i += gridDim.x * 256) {
        const int c = (i & 31) << 2;
        float4 v = *(float4*)(out + (size_t)i * 4);
        v.x = fmaxf(fmaf(v.x, sc[c + 0], sh[c + 0]), 0.f);
        v.y = fmaxf(fmaf(v.y, sc[c + 1], sh[c + 1]), 0.f);
        v.z = fmaxf(fmaf(v.z, sc[c + 2], sh[c + 2]), 0.f);
        v.w = fmaxf(fmaf(v.w, sc[c + 3], sh[c + 3]), 0.f);
        *(float4*)(out + (size_t)i * 4) = v;
    }
}

extern "C" void kernel_launch(void* const* d_in, const int* in_sizes, int n_in,
                              void* d_out, int out_size, void* d_ws, size_t ws_size,
                              hipStream_t stream)
{
    const float* X      = (const float*)d_in[0];
    const float* bases  = (const float*)d_in[1];
    const float* coeff  = (const float*)d_in[2];
    const float* Wl     = (const float*)d_in[3];
    const float* bl     = (const float*)d_in[4];
    const float* gamma  = (const float*)d_in[5];
    const float* beta   = (const float*)d_in[6];
    const int*   eidx   = (const int*)d_in[7];
    const int*   etype  = (const int*)d_in[8];
    float* out = (float*)d_out;

    float* ws = (float*)d_ws;
    ushort_t* WT     = (ushort_t*)(ws + WT_OFF);
    ushort_t* XG_G   = (ushort_t*)(ws + XGG_OFF);
    ushort_t* Xbf    = (ushort_t*)(ws + XBF_OFF);
    int*      cnt    = (int*)(ws + CNT_OFF);
    int*      curs   = (int*)(ws + CUR_OFF);
    int*      bsum   = (int*)(ws + BSUM_OFF);
    int*      bscan  = (int*)(ws + BSCN_OFF);
    float*    colsum = ws + CS_OFF;
    float*    colsq  = ws + CSQ_OFF;
    uint32_t* epack  = (uint32_t*)d_out;   // dead before k_gemm_f writes out

    // zero cnt..colsq
    hipMemsetAsync(cnt, 0, (CSQ_OFF + 128 - CNT_OFF) * sizeof(float), stream);

    const int nblk_scan = (NN + 511) / 512;   // 98

    k_pre<<<5493, 256, 0, stream>>>(X, Wl, bases, eidx, WT, Xbf, cnt);
    k_scan1<<<nblk_scan, 256, 0, stream>>>(cnt, curs, bsum);
    k_scan2<<<1, 128, 0, stream>>>(bsum, bscan, nblk_scan);
    k_scan3<<<nblk_scan, 256, 0, stream>>>(curs, bscan);
    k_scatter<<<2048, 256, 0, stream>>>(eidx, etype, curs, epack);
    k_gather<<<3125, 256, 0, stream>>>(Xbf, epack, cnt, curs, coeff, XG_G);
    k_gemm_f<<<GSTRIDE, 256, 0, stream>>>(XG_G, WT, Xbf, bl, cnt,
                                          out, colsum, colsq);
    k_bn_relu<<<1024, 256, 0, stream>>>(out, colsum, colsq, gamma, beta);
}